// Round 10
// baseline (70.116 us; speedup 1.0000x reference)
//
#include <hip/hip_runtime.h>
#include <math.h>

// IN_C=3, DIM=256, OUT_C=256, N_PIECES=20, BATCH=16, SET_N=128

#if __has_builtin(__builtin_amdgcn_exp2f)
#define EXP2F(x) __builtin_amdgcn_exp2f(x)
#else
#define EXP2F(x) exp2f(x)
#endif

#define NBLK 1024u

__device__ __forceinline__ float pool_weight(const float* __restrict__ pw, int j)
{
    float ratio = (float)j / 127.0f;
    float idx_f = 20.0f * ratio;
    int idx = (int)idx_f;
    float frac = idx_f - (float)idx;
    int idx2 = idx + 1 > 20 ? 20 : idx + 1;
    return (1.0f - frac) * pw[idx] + frac * pw[idx2];
}

// one online-softmax step (log2 domain): v = s*scal - B
#define OSTEP(sv, bv, scal, m, se, sd)                      \
    {                                                       \
        float v_  = fmaf((sv), (scal), -(bv));              \
        float mn_ = fmaxf((m), v_);                         \
        float sc_ = EXP2F((m) - mn_);                       \
        float e_  = EXP2F(v_ - mn_);                        \
        (se) = fmaf((se), sc_, e_);                         \
        (sd) = fmaf((sd), sc_, e_ * (sv));                  \
        (m)  = mn_;                                         \
    }

// ---------------------------------------------------------------------------
// ONE kernel: conv1+conv2+fspool (R9 phases verbatim), then a fence-free
// completion gate: every block does one device-scope atomicAdd; the last 16
// finishers each run the MLP tail for one batch. No threadfence, <=15 short
// polls total.
// ---------------------------------------------------------------------------
__global__ __launch_bounds__(256) void fused_lastgate(
    const float* __restrict__ x,   const float* __restrict__ w1,
    const float* __restrict__ b1,  const float* __restrict__ W2,
    const float* __restrict__ b2,  const float* __restrict__ pool_w,
    const float* __restrict__ L1w, const float* __restrict__ L1b,
    const float* __restrict__ L2w, const float* __restrict__ L2b,
    const float* __restrict__ C1w, const float* __restrict__ C1b,
    const float* __restrict__ C2w, const float* __restrict__ C2b,
    float* __restrict__ pooled, unsigned* __restrict__ cnt,
    float* __restrict__ out)
{
    const float LOG2E = 1.4426950408889634f;
    __shared__ float4 w1p[256];      // (w1[k,0..2], b1[k])          4 KB
    __shared__ float  Ast[4][32];    // W2 sub-tile [d-local][k]     0.5 KB
    __shared__ float2 Bsp[32][66];   // relu(conv1) pairs (n, n+64)  16.9 KB
    __shared__ float  ss[4][128];    // s values per row             2 KB
    __shared__ float  bb[4][128];    // B*log2e per row              2 KB
    __shared__ float  za[256], zb[256];
    __shared__ unsigned sOld;

    int tid = threadIdx.x;
    int blk = blockIdx.x;
    int b   = blk >> 6;              // batch 0..15
    int c0  = (blk & 63) << 2;       // 4-row channel group

    int wid = tid >> 6, l = tid & 63;
    int ng  = tid & 31;
    int kg  = tid >> 5;
    int n0  = ng * 2;

    // one-time staging: w1 params to LDS, own x columns to registers
    w1p[tid] = make_float4(w1[tid*3], w1[tid*3+1], w1[tid*3+2], b1[tid]);
    const float* xb = x + b * 384;
    float x00 = xb[n0],            x01 = xb[n0 + 1];
    float x0a = xb[n0 + 64],       x0b = xb[n0 + 65];
    float x10 = xb[128 + n0],      x11 = xb[128 + n0 + 1];
    float x1a = xb[128 + n0 + 64], x1b = xb[128 + n0 + 65];
    float x20 = xb[256 + n0],      x21 = xb[256 + n0 + 1];
    float x2a = xb[256 + n0 + 64], x2b = xb[256 + n0 + 65];
    __syncthreads();

    float acc0 = 0.f, acc1 = 0.f;

    for (int k0 = 0; k0 < 256; k0 += 32) {
        if (tid < 128)
            Ast[tid >> 5][tid & 31] =
                W2[(c0 + (tid >> 5)) * 256 + k0 + (tid & 31)];
        #pragma unroll
        for (int q = 0; q < 4; q++) {
            int krel = kg * 4 + q;
            float4 wv = w1p[k0 + krel];
            float h0 = fmaxf(fmaf(wv.x,x00, fmaf(wv.y,x10, fmaf(wv.z,x20, wv.w))), 0.f);
            float h1 = fmaxf(fmaf(wv.x,x01, fmaf(wv.y,x11, fmaf(wv.z,x21, wv.w))), 0.f);
            float ha = fmaxf(fmaf(wv.x,x0a, fmaf(wv.y,x1a, fmaf(wv.z,x2a, wv.w))), 0.f);
            float hb = fmaxf(fmaf(wv.x,x0b, fmaf(wv.y,x1b, fmaf(wv.z,x2b, wv.w))), 0.f);
            *(float4*)&Bsp[krel][n0] = make_float4(h0, ha, h1, hb);
        }
        __syncthreads();
        float4 a4[8];
        #pragma unroll
        for (int q = 0; q < 8; q++)
            a4[q] = *(const float4*)&Ast[wid][q * 4];
        #pragma unroll
        for (int kk = 0; kk < 32; kk++) {
            float a = ((const float*)a4)[kk];
            float2 bv = Bsp[kk][l];
            acc0 = fmaf(a, bv.x, acc0);
            acc1 = fmaf(a, bv.y, acc1);
        }
        __syncthreads();
    }

    // ---- fspool (wave-local; wave wid owns row c0+wid) ----
    float bias = b2[c0 + wid];
    float s0 = acc0 + bias, s1 = acc1 + bias;
    ss[wid][l]      = s0;
    ss[wid][l + 64] = s1;

    float a0=0,a1=0,a2=0,a3=0, g0=0,g1=0,g2=0,g3=0;
    #pragma unroll 8
    for (int j = 0; j < 128; j += 4) {
        float4 s4 = *(const float4*)&ss[wid][j];
        a0 += fabsf(s0 - s4.x); a1 += fabsf(s0 - s4.y);
        a2 += fabsf(s0 - s4.z); a3 += fabsf(s0 - s4.w);
        g0 += fabsf(s1 - s4.x); g1 += fabsf(s1 - s4.y);
        g2 += fabsf(s1 - s4.z); g3 += fabsf(s1 - s4.w);
    }
    bb[wid][l]      = ((a0+a1)+(a2+a3)) * LOG2E;
    bb[wid][l + 64] = ((g0+g1)+(g2+g3)) * LOG2E;

    float scal0 = (float)(127 - 2 * l) * LOG2E;
    float scal1 = (float)(-1 - 2 * l) * LOG2E;
    float mA0=-1e30f, mB0=-1e30f, mA1=-1e30f, mB1=-1e30f;
    float seA0=0,seB0=0,sdA0=0,sdB0=0;
    float seA1=0,seB1=0,sdA1=0,sdB1=0;
    #pragma unroll 4
    for (int i = 0; i < 128; i += 4) {
        float4 s4 = *(const float4*)&ss[wid][i];
        float4 b4 = *(const float4*)&bb[wid][i];
        OSTEP(s4.x, b4.x, scal0, mA0, seA0, sdA0);
        OSTEP(s4.y, b4.y, scal0, mB0, seB0, sdB0);
        OSTEP(s4.z, b4.z, scal0, mA0, seA0, sdA0);
        OSTEP(s4.w, b4.w, scal0, mB0, seB0, sdB0);
        OSTEP(s4.x, b4.x, scal1, mA1, seA1, sdA1);
        OSTEP(s4.y, b4.y, scal1, mB1, seB1, sdB1);
        OSTEP(s4.z, b4.z, scal1, mA1, seA1, sdA1);
        OSTEP(s4.w, b4.w, scal1, mB1, seB1, sdB1);
    }
    float m0  = fmaxf(mA0, mB0);
    float scA = EXP2F(mA0 - m0), scB = EXP2F(mB0 - m0);
    float xs0 = (sdA0 * scA + sdB0 * scB) / (seA0 * scA + seB0 * scB);
    float m1  = fmaxf(mA1, mB1);
    float tA  = EXP2F(mA1 - m1), tB = EXP2F(mB1 - m1);
    float xs1 = (sdA1 * tA + sdB1 * tB) / (seA1 * tA + seB1 * tB);

    int c = c0 + wid;
    const float* pw = pool_w + c * 21;
    float part = xs0 * pool_weight(pw, l) + xs1 * pool_weight(pw, l + 64);
    #pragma unroll
    for (int off = 32; off > 0; off >>= 1)
        part += __shfl_xor(part, off);
    if (l == 0)
        __hip_atomic_store(&pooled[b * 256 + c], part,
                           __ATOMIC_RELAXED, __HIP_MEMORY_SCOPE_AGENT);

    // ---- completion gate: last 16 finishers run the tail ----
    __syncthreads();                      // drains each wave's vmcnt
    if (tid == 0)
        sOld = __hip_atomic_fetch_add(cnt, 1u, __ATOMIC_ACQ_REL,
                                      __HIP_MEMORY_SCOPE_AGENT);
    __syncthreads();
    unsigned old = sOld;
    if (old < NBLK - 16u) return;

    int bt = (int)(old - (NBLK - 16u));   // batch 0..15
    if (tid == 0 && old != NBLK - 1u) {
        while (__hip_atomic_load(cnt, __ATOMIC_ACQUIRE,
                                 __HIP_MEMORY_SCOPE_AGENT) < NBLK)
            __builtin_amdgcn_s_sleep(2);
    }
    __syncthreads();

    // ---- MLP tail for batch bt (R8-validated body) ----
    za[tid] = __hip_atomic_load(&pooled[bt * 256 + tid],
                                __ATOMIC_RELAXED, __HIP_MEMORY_SCOPE_AGENT);
    __syncthreads();
    {   // lin1 + relu -> zb
        float acc = L1b[tid];
        const float* wr = L1w + tid * 256;
        #pragma unroll 8
        for (int k = 0; k < 256; k += 4) {
            float4 wv = *(const float4*)(wr + k);
            float4 iv = *(const float4*)(&za[k]);
            acc = fmaf(wv.x, iv.x, acc); acc = fmaf(wv.y, iv.y, acc);
            acc = fmaf(wv.z, iv.z, acc); acc = fmaf(wv.w, iv.w, acc);
        }
        zb[tid] = fmaxf(acc, 0.f);
    }
    __syncthreads();
    {   // lin2 -> za
        float acc = L2b[tid];
        const float* wr = L2w + tid * 256;
        #pragma unroll 8
        for (int k = 0; k < 256; k += 4) {
            float4 wv = *(const float4*)(wr + k);
            float4 iv = *(const float4*)(&zb[k]);
            acc = fmaf(wv.x, iv.x, acc); acc = fmaf(wv.y, iv.y, acc);
            acc = fmaf(wv.z, iv.z, acc); acc = fmaf(wv.w, iv.w, acc);
        }
        za[tid] = acc;
    }
    __syncthreads();
    {   // cls1 + relu -> zb
        float acc = C1b[tid];
        const float* wr = C1w + tid * 256;
        #pragma unroll 8
        for (int k = 0; k < 256; k += 4) {
            float4 wv = *(const float4*)(wr + k);
            float4 iv = *(const float4*)(&za[k]);
            acc = fmaf(wv.x, iv.x, acc); acc = fmaf(wv.y, iv.y, acc);
            acc = fmaf(wv.z, iv.z, acc); acc = fmaf(wv.w, iv.w, acc);
        }
        zb[tid] = fmaxf(acc, 0.f);
    }
    __syncthreads();
    if (tid < 160) {   // cls2: 10 outputs x 16 lanes
        int o = tid >> 4, kk = tid & 15;
        const float* wr = C2w + o * 256;
        float pp = 0.f;
        #pragma unroll
        for (int k = kk * 16; k < kk * 16 + 16; k++)
            pp = fmaf(zb[k], wr[k], pp);
        pp += __shfl_down(pp, 8, 16);
        pp += __shfl_down(pp, 4, 16);
        pp += __shfl_down(pp, 2, 16);
        pp += __shfl_down(pp, 1, 16);
        if (kk == 0) out[bt * 10 + o] = pp + C2b[o];
    }
}

// ---------------------------------------------------------------------------
extern "C" void kernel_launch(void* const* d_in, const int* in_sizes, int n_in,
                              void* d_out, int out_size, void* d_ws, size_t ws_size,
                              hipStream_t stream)
{
    (void)in_sizes; (void)n_in; (void)out_size; (void)ws_size;
    const float* x       = (const float*)d_in[0];
    const float* conv1_w = (const float*)d_in[1];
    const float* conv1_b = (const float*)d_in[2];
    const float* conv2_w = (const float*)d_in[3];
    const float* conv2_b = (const float*)d_in[4];
    const float* pool_w  = (const float*)d_in[5];
    const float* lin1_w  = (const float*)d_in[6];
    const float* lin1_b  = (const float*)d_in[7];
    const float* lin2_w  = (const float*)d_in[8];
    const float* lin2_b  = (const float*)d_in[9];
    const float* cls1_w  = (const float*)d_in[10];
    const float* cls1_b  = (const float*)d_in[11];
    const float* cls2_w  = (const float*)d_in[12];
    const float* cls2_b  = (const float*)d_in[13];
    float* out = (float*)d_out;

    float*    pooled = (float*)d_ws;                 // 4096 floats
    unsigned* cnt    = (unsigned*)((float*)d_ws + 4096);

    hipMemsetAsync(cnt, 0, sizeof(unsigned), stream);
    fused_lastgate<<<NBLK, 256, 0, stream>>>(
        x, conv1_w, conv1_b, conv2_w, conv2_b, pool_w,
        lin1_w, lin1_b, lin2_w, lin2_b, cls1_w, cls1_b, cls2_w, cls2_b,
        pooled, cnt, out);
}

// Round 11
// 65.566 us; speedup vs baseline: 1.0694x; 1.0694x over previous
//
#include <hip/hip_runtime.h>
#include <math.h>

// IN_C=3, DIM=256, OUT_C=256, N_PIECES=20, BATCH=16, SET_N=128

#if __has_builtin(__builtin_amdgcn_exp2f)
#define EXP2F(x) __builtin_amdgcn_exp2f(x)
#else
#define EXP2F(x) exp2f(x)
#endif

__device__ __forceinline__ float pool_weight(const float* __restrict__ pw, int j)
{
    float ratio = (float)j / 127.0f;
    float idx_f = 20.0f * ratio;
    int idx = (int)idx_f;
    float frac = idx_f - (float)idx;
    int idx2 = idx + 1 > 20 ? 20 : idx + 1;
    return (1.0f - frac) * pw[idx] + frac * pw[idx2];
}

// ---------------------------------------------------------------------------
// K1: conv1+conv2+fspool at FULL occupancy.
// 2048 blocks x 256 thr (4 waves). Block = (b, 2 channel rows).
// GEMM: waves 0,1 compute rows 0,1 (2 cols/lane, R9-proven b64 reads);
//       all 4 waves stage Bsp (BK=16). fspool: (r,h)=(wid&1,wid>>1),
//       1 j per lane -> 8192 waves = 32 waves/CU.
// LDS ~14.6 KB -> 8 blocks/CU. launch_bounds(256,8) caps VGPR at 64.
// ---------------------------------------------------------------------------
__global__ __launch_bounds__(256, 8) void conv_pool_kernel(
    const float* __restrict__ x,   const float* __restrict__ w1,
    const float* __restrict__ b1,  const float* __restrict__ W2,
    const float* __restrict__ b2,  const float* __restrict__ pool_w,
    float* __restrict__ pooled)
{
    const float LOG2E = 1.4426950408889634f;
    __shared__ __align__(16) float4 w1p[256];    // (w1[k,0..2], b1[k])  4 KB
    __shared__ __align__(16) float  Ast[2][16];  // W2 sub-tile          128 B
    __shared__ __align__(16) float2 Bsp[16][66]; // conv1 pairs (n,n+64) 8.25 KB
    __shared__ __align__(16) float  ss[2][128];  // s values per row     1 KB
    __shared__ __align__(16) float  bb[2][128];  // B*log2e per row      1 KB
    __shared__ float partial[4];

    int tid = threadIdx.x;
    int blk = blockIdx.x;
    int b   = blk >> 7;               // batch 0..15
    int c0  = (blk & 127) << 1;       // 2-row channel group

    int wid = tid >> 6, l = tid & 63;
    int r   = wid & 1,  h = wid >> 1; // fspool mapping
    int ng  = tid & 31, kg = tid >> 5;
    int n0  = ng * 2;

    // one-time staging: w1 params to LDS, own x columns to registers
    w1p[tid] = make_float4(w1[tid*3], w1[tid*3+1], w1[tid*3+2], b1[tid]);
    const float* xb = x + b * 384;
    float x00 = xb[n0],            x01 = xb[n0 + 1];
    float x0a = xb[n0 + 64],       x0b = xb[n0 + 65];
    float x10 = xb[128 + n0],      x11 = xb[128 + n0 + 1];
    float x1a = xb[128 + n0 + 64], x1b = xb[128 + n0 + 65];
    float x20 = xb[256 + n0],      x21 = xb[256 + n0 + 1];
    float x2a = xb[256 + n0 + 64], x2b = xb[256 + n0 + 65];
    __syncthreads();

    float acc0 = 0.f, acc1 = 0.f;

    for (int k0 = 0; k0 < 256; k0 += 16) {
        if (tid < 32)
            Ast[tid >> 4][tid & 15] =
                W2[(c0 + (tid >> 4)) * 256 + k0 + (tid & 15)];
        #pragma unroll
        for (int q = 0; q < 2; q++) {
            int krel = kg * 2 + q;
            float4 wv = w1p[k0 + krel];
            float h0 = fmaxf(fmaf(wv.x,x00, fmaf(wv.y,x10, fmaf(wv.z,x20, wv.w))), 0.f);
            float h1 = fmaxf(fmaf(wv.x,x01, fmaf(wv.y,x11, fmaf(wv.z,x21, wv.w))), 0.f);
            float ha = fmaxf(fmaf(wv.x,x0a, fmaf(wv.y,x1a, fmaf(wv.z,x2a, wv.w))), 0.f);
            float hb = fmaxf(fmaf(wv.x,x0b, fmaf(wv.y,x1b, fmaf(wv.z,x2b, wv.w))), 0.f);
            *(float4*)&Bsp[krel][n0] = make_float4(h0, ha, h1, hb);
        }
        __syncthreads();
        if (wid < 2) {                 // GEMM waves: row = wid
            float4 a4[4];
            #pragma unroll
            for (int q = 0; q < 4; q++)
                a4[q] = *(const float4*)&Ast[wid][q * 4];
            #pragma unroll
            for (int kk = 0; kk < 16; kk++) {
                float a = ((const float*)a4)[kk];
                float2 bv = Bsp[kk][l];
                acc0 = fmaf(a, bv.x, acc0);
                acc1 = fmaf(a, bv.y, acc1);
            }
        }
        __syncthreads();
    }

    if (wid < 2) {
        float bias = b2[c0 + wid];
        ss[wid][l]      = acc0 + bias;
        ss[wid][l + 64] = acc1 + bias;
    }
    __syncthreads();

    // ---- fspool: wave (r,h), lane owns i = j = h*64+l ----
    int i = h * 64 + l;
    float si = ss[r][i];

    float a0 = 0.f, a1 = 0.f, a2 = 0.f, a3 = 0.f;
    #pragma unroll 8
    for (int j = 0; j < 128; j += 4) {
        float4 s4 = *(const float4*)&ss[r][j];
        a0 += fabsf(si - s4.x); a1 += fabsf(si - s4.y);
        a2 += fabsf(si - s4.z); a3 += fabsf(si - s4.w);
    }
    bb[r][i] = ((a0 + a1) + (a2 + a3)) * LOG2E;
    __syncthreads();

    float scal = (float)(127 - 2 * i) * LOG2E;
    float m0 = -1e30f, m1 = -1e30f, m2 = -1e30f, m3 = -1e30f;
    #pragma unroll 8
    for (int k = 0; k < 128; k += 4) {
        float4 s4 = *(const float4*)&ss[r][k];
        float4 b4 = *(const float4*)&bb[r][k];
        m0 = fmaxf(m0, fmaf(s4.x, scal, -b4.x));
        m1 = fmaxf(m1, fmaf(s4.y, scal, -b4.y));
        m2 = fmaxf(m2, fmaf(s4.z, scal, -b4.z));
        m3 = fmaxf(m3, fmaf(s4.w, scal, -b4.w));
    }
    float m = fmaxf(fmaxf(m0, m1), fmaxf(m2, m3));

    float se0 = 0.f, se1 = 0.f, se2 = 0.f, se3 = 0.f;
    float sd0 = 0.f, sd1 = 0.f, sd2 = 0.f, sd3 = 0.f;
    #pragma unroll 4
    for (int k = 0; k < 128; k += 4) {
        float4 s4 = *(const float4*)&ss[r][k];
        float4 b4 = *(const float4*)&bb[r][k];
        float e0 = EXP2F(fmaf(s4.x, scal, -b4.x) - m);
        float e1 = EXP2F(fmaf(s4.y, scal, -b4.y) - m);
        float e2 = EXP2F(fmaf(s4.z, scal, -b4.z) - m);
        float e3 = EXP2F(fmaf(s4.w, scal, -b4.w) - m);
        se0 += e0; sd0 = fmaf(e0, s4.x, sd0);
        se1 += e1; sd1 = fmaf(e1, s4.y, sd1);
        se2 += e2; sd2 = fmaf(e2, s4.z, sd2);
        se3 += e3; sd3 = fmaf(e3, s4.w, sd3);
    }
    float xs = ((sd0 + sd1) + (sd2 + sd3)) / ((se0 + se1) + (se2 + se3));

    float part = xs * pool_weight(pool_w + (c0 + r) * 21, i);
    #pragma unroll
    for (int off = 32; off > 0; off >>= 1)
        part += __shfl_xor(part, off);
    if (l == 0) partial[wid] = part;
    __syncthreads();
    if (tid < 2)
        pooled[b * 256 + c0 + tid] = partial[tid] + partial[tid + 2];
}

// ---------------------------------------------------------------------------
// K2: MLP tail. 16 blocks x 512 thr (R9 verbatim).
// ---------------------------------------------------------------------------
__device__ __forceinline__ void dense512(
    const float* __restrict__ W, const float* __restrict__ Bv,
    const float* in_lds, float* out_lds, int tid, bool do_relu)
{
    int o = tid >> 1, p = tid & 1;
    const float* wr = W + o * 256 + p * 128;
    const float* ir = in_lds + p * 128;
    float acc = 0.f;
    #pragma unroll
    for (int k = 0; k < 128; k += 4) {
        float4 wv = *(const float4*)(wr + k);
        float4 iv = *(const float4*)(ir + k);
        acc = fmaf(wv.x, iv.x, acc); acc = fmaf(wv.y, iv.y, acc);
        acc = fmaf(wv.z, iv.z, acc); acc = fmaf(wv.w, iv.w, acc);
    }
    acc += __shfl_xor(acc, 1);
    if (p == 0) {
        acc += Bv[o];
        out_lds[o] = do_relu ? fmaxf(acc, 0.f) : acc;
    }
}

__global__ __launch_bounds__(512) void tail_kernel(
    const float* __restrict__ pooled,
    const float* __restrict__ L1w, const float* __restrict__ L1b,
    const float* __restrict__ L2w, const float* __restrict__ L2b,
    const float* __restrict__ C1w, const float* __restrict__ C1b,
    const float* __restrict__ C2w, const float* __restrict__ C2b,
    float* __restrict__ out)
{
    __shared__ float za[256], zb[256];
    int bt = blockIdx.x, tid = threadIdx.x;
    if (tid < 256) za[tid] = pooled[bt * 256 + tid];
    __syncthreads();
    dense512(L1w, L1b, za, zb, tid, true);
    __syncthreads();
    dense512(L2w, L2b, zb, za, tid, false);
    __syncthreads();
    dense512(C1w, C1b, za, zb, tid, true);
    __syncthreads();
    if (tid < 320) {   // cls2: 10 outputs x 32 lanes, 8 k each
        int o = tid >> 5, kb = tid & 31;
        const float* wr = C2w + o * 256 + kb * 8;
        const float* ir = zb + kb * 8;
        float4 w0 = *(const float4*)(wr);
        float4 w1v = *(const float4*)(wr + 4);
        float4 i0 = *(const float4*)(ir);
        float4 i1 = *(const float4*)(ir + 4);
        float p = fmaf(w0.x,i0.x, fmaf(w0.y,i0.y, fmaf(w0.z,i0.z,
                  fmaf(w0.w,i0.w, fmaf(w1v.x,i1.x, fmaf(w1v.y,i1.y,
                  fmaf(w1v.z,i1.z, w1v.w*i1.w)))))));
        #pragma unroll
        for (int off = 16; off > 0; off >>= 1)
            p += __shfl_xor(p, off, 32);
        if (kb == 0) out[bt * 10 + o] = p + C2b[o];
    }
}

// ---------------------------------------------------------------------------
extern "C" void kernel_launch(void* const* d_in, const int* in_sizes, int n_in,
                              void* d_out, int out_size, void* d_ws, size_t ws_size,
                              hipStream_t stream)
{
    (void)in_sizes; (void)n_in; (void)out_size; (void)ws_size;
    const float* x       = (const float*)d_in[0];
    const float* conv1_w = (const float*)d_in[1];
    const float* conv1_b = (const float*)d_in[2];
    const float* conv2_w = (const float*)d_in[3];
    const float* conv2_b = (const float*)d_in[4];
    const float* pool_w  = (const float*)d_in[5];
    const float* lin1_w  = (const float*)d_in[6];
    const float* lin1_b  = (const float*)d_in[7];
    const float* lin2_w  = (const float*)d_in[8];
    const float* lin2_b  = (const float*)d_in[9];
    const float* cls1_w  = (const float*)d_in[10];
    const float* cls1_b  = (const float*)d_in[11];
    const float* cls2_w  = (const float*)d_in[12];
    const float* cls2_b  = (const float*)d_in[13];
    float* out = (float*)d_out;

    float* pooled = (float*)d_ws;        // 4096 floats

    conv_pool_kernel<<<2048, 256, 0, stream>>>(
        x, conv1_w, conv1_b, conv2_w, conv2_b, pool_w, pooled);
    tail_kernel<<<16, 512, 0, stream>>>(pooled,
        lin1_w, lin1_b, lin2_w, lin2_b, cls1_w, cls1_b, cls2_w, cls2_b, out);
}

// Round 12
// 57.485 us; speedup vs baseline: 1.2197x; 1.1406x over previous
//
#include <hip/hip_runtime.h>
#include <math.h>

// IN_C=3, DIM=256, OUT_C=256, N_PIECES=20, BATCH=16, SET_N=128

#if __has_builtin(__builtin_amdgcn_exp2f)
#define EXP2F(x) __builtin_amdgcn_exp2f(x)
#else
#define EXP2F(x) exp2f(x)
#endif

#define LOG2E 1.4426950408889634f

__device__ __forceinline__ float pool_weight(const float* __restrict__ pw, int j)
{
    float ratio = (float)j / 127.0f;
    float idx_f = 20.0f * ratio;
    int idx = (int)idx_f;
    float frac = idx_f - (float)idx;
    int idx2 = idx + 1 > 20 ? 20 : idx + 1;
    return (1.0f - frac) * pw[idx] + frac * pw[idx2];
}

// ---------------------------------------------------------------------------
// K1: conv1+conv2+fspool, 1024 blocks x 512 thr (8 waves), 4 rows/block.
// GEMM: lane = (col = tid&127, kq = tid>>7); each lane accumulates ALL 4 rows
//   over its k-quarter (pairs t = 4p+kq). One b64 Bsp2 read feeds 8 fmas.
//   A-operand: AstT[k] = float4(W2[c0+0..3][k]) broadcast. kq-partials reduced
//   through LDS into ss[4][128].
// fspool: wave wid -> (r = wid&3, h = wid>>2), lane owns i = j = h*64+l.
//   2-pass softmax, broadcast b128 reads, 4-way split chains.
// ---------------------------------------------------------------------------
__global__ __launch_bounds__(512, 8) void conv_pool_kernel(
    const float* __restrict__ x,   const float* __restrict__ w1,
    const float* __restrict__ b1,  const float* __restrict__ W2,
    const float* __restrict__ b2,  const float* __restrict__ pool_w,
    float* __restrict__ pooled)
{
    __shared__ float4 w1p[256];          // (w1[k,0..2], b1[k])        4 KB
    __shared__ float4 AstT[32];          // (A[r0..3][k]) per step-k   0.5 KB
    __shared__ float2 Bsp2[16][132];     // (h_{2t}, h_{2t+1})[n]      16.5 KB
    __shared__ float4 Part[4][128];      // kq-partials (acc r0..3)    8 KB
    __shared__ float  ss[4][128];        // s values                   2 KB
    __shared__ float  bb[4][128];        // B*log2e                    2 KB
    __shared__ float  partial[8];

    int tid = threadIdx.x;
    int blk = blockIdx.x;
    int b   = blk >> 6;                  // batch 0..15
    int c0  = (blk & 63) << 2;           // 4-row channel group

    // conv1-staging role
    int k2 = tid >> 5;                   // kk-pair 0..15
    int n0 = (tid & 31) * 4;             // n quad
    // GEMM role
    int col = tid & 127;
    int kq  = tid >> 7;                  // k-quarter 0..3
    // fspool role
    int wid = tid >> 6, l = tid & 63;
    int r   = wid & 3,  h = wid >> 2;
    int i   = h * 64 + l;

    if (tid < 256)
        w1p[tid] = make_float4(w1[tid*3], w1[tid*3+1], w1[tid*3+2], b1[tid]);
    const float* xb = x + b * 384;
    float4 xc0 = *(const float4*)(xb + n0);
    float4 xc1 = *(const float4*)(xb + 128 + n0);
    float4 xc2 = *(const float4*)(xb + 256 + n0);
    __syncthreads();

    float ac0 = 0.f, ac1 = 0.f, ac2 = 0.f, ac3 = 0.f;

    for (int k0 = 0; k0 < 256; k0 += 32) {
        if (tid < 32) {
            int k = k0 + tid;
            AstT[tid] = make_float4(W2[(c0+0)*256 + k], W2[(c0+1)*256 + k],
                                    W2[(c0+2)*256 + k], W2[(c0+3)*256 + k]);
        }
        {   // conv1: kk = 2*k2, 2*k2+1 for n0..n0+3, packed as kk-pairs
            float4 wv0 = w1p[k0 + 2*k2];
            float4 wv1 = w1p[k0 + 2*k2 + 1];
            float h00 = fmaxf(fmaf(wv0.x,xc0.x, fmaf(wv0.y,xc1.x, fmaf(wv0.z,xc2.x, wv0.w))), 0.f);
            float h01 = fmaxf(fmaf(wv0.x,xc0.y, fmaf(wv0.y,xc1.y, fmaf(wv0.z,xc2.y, wv0.w))), 0.f);
            float h02 = fmaxf(fmaf(wv0.x,xc0.z, fmaf(wv0.y,xc1.z, fmaf(wv0.z,xc2.z, wv0.w))), 0.f);
            float h03 = fmaxf(fmaf(wv0.x,xc0.w, fmaf(wv0.y,xc1.w, fmaf(wv0.z,xc2.w, wv0.w))), 0.f);
            float h10 = fmaxf(fmaf(wv1.x,xc0.x, fmaf(wv1.y,xc1.x, fmaf(wv1.z,xc2.x, wv1.w))), 0.f);
            float h11 = fmaxf(fmaf(wv1.x,xc0.y, fmaf(wv1.y,xc1.y, fmaf(wv1.z,xc2.y, wv1.w))), 0.f);
            float h12 = fmaxf(fmaf(wv1.x,xc0.z, fmaf(wv1.y,xc1.z, fmaf(wv1.z,xc2.z, wv1.w))), 0.f);
            float h13 = fmaxf(fmaf(wv1.x,xc0.w, fmaf(wv1.y,xc1.w, fmaf(wv1.z,xc2.w, wv1.w))), 0.f);
            *(float4*)&Bsp2[k2][n0]     = make_float4(h00, h10, h01, h11);
            *(float4*)&Bsp2[k2][n0 + 2] = make_float4(h02, h12, h03, h13);
        }
        __syncthreads();
        #pragma unroll
        for (int p = 0; p < 4; p++) {
            int t = 4*p + kq;
            float2 bv = Bsp2[t][col];
            float4 a0 = AstT[2*t];
            float4 a1 = AstT[2*t + 1];
            ac0 = fmaf(a0.x, bv.x, ac0); ac0 = fmaf(a1.x, bv.y, ac0);
            ac1 = fmaf(a0.y, bv.x, ac1); ac1 = fmaf(a1.y, bv.y, ac1);
            ac2 = fmaf(a0.z, bv.x, ac2); ac2 = fmaf(a1.z, bv.y, ac2);
            ac3 = fmaf(a0.w, bv.x, ac3); ac3 = fmaf(a1.w, bv.y, ac3);
        }
        __syncthreads();
    }

    // ---- kq-partial reduce -> ss[r][i], s_own stays in register ----
    Part[kq][col] = make_float4(ac0, ac1, ac2, ac3);
    __syncthreads();
    const float* pf = (const float*)Part;   // [4][128][4] floats
    float s_own;
    {
        float v0 = pf[(0*128 + i)*4 + r];
        float v1 = pf[(1*128 + i)*4 + r];
        float v2 = pf[(2*128 + i)*4 + r];
        float v3 = pf[(3*128 + i)*4 + r];
        s_own = ((v0 + v1) + (v2 + v3)) + b2[c0 + r];
        ss[r][i] = s_own;
    }
    __syncthreads();

    // ---- fspool: lane owns i = j for row r ----
    float sa0=0.f, sa1=0.f, sa2=0.f, sa3=0.f;
    #pragma unroll 8
    for (int j = 0; j < 128; j += 4) {
        float4 s4 = *(const float4*)&ss[r][j];
        sa0 += fabsf(s_own - s4.x); sa1 += fabsf(s_own - s4.y);
        sa2 += fabsf(s_own - s4.z); sa3 += fabsf(s_own - s4.w);
    }
    bb[r][i] = ((sa0+sa1)+(sa2+sa3)) * LOG2E;
    __syncthreads();

    float scal = (float)(127 - 2*i) * LOG2E;
    float m0=-1e30f, m1=-1e30f, m2=-1e30f, m3=-1e30f;
    #pragma unroll 8
    for (int k = 0; k < 128; k += 4) {
        float4 s4 = *(const float4*)&ss[r][k];
        float4 b4 = *(const float4*)&bb[r][k];
        m0 = fmaxf(m0, fmaf(s4.x, scal, -b4.x));
        m1 = fmaxf(m1, fmaf(s4.y, scal, -b4.y));
        m2 = fmaxf(m2, fmaf(s4.z, scal, -b4.z));
        m3 = fmaxf(m3, fmaf(s4.w, scal, -b4.w));
    }
    float m = fmaxf(fmaxf(m0, m1), fmaxf(m2, m3));

    float se0=0.f, se1=0.f, se2=0.f, se3=0.f;
    float sd0=0.f, sd1=0.f, sd2=0.f, sd3=0.f;
    #pragma unroll 4
    for (int k = 0; k < 128; k += 4) {
        float4 s4 = *(const float4*)&ss[r][k];
        float4 b4 = *(const float4*)&bb[r][k];
        float e0 = EXP2F(fmaf(s4.x, scal, -b4.x) - m);
        float e1 = EXP2F(fmaf(s4.y, scal, -b4.y) - m);
        float e2 = EXP2F(fmaf(s4.z, scal, -b4.z) - m);
        float e3 = EXP2F(fmaf(s4.w, scal, -b4.w) - m);
        se0 += e0; sd0 = fmaf(e0, s4.x, sd0);
        se1 += e1; sd1 = fmaf(e1, s4.y, sd1);
        se2 += e2; sd2 = fmaf(e2, s4.z, sd2);
        se3 += e3; sd3 = fmaf(e3, s4.w, sd3);
    }
    float xs = ((sd0+sd1)+(sd2+sd3)) / ((se0+se1)+(se2+se3));

    float part = xs * pool_weight(pool_w + (c0 + r) * 21, i);
    #pragma unroll
    for (int off = 32; off > 0; off >>= 1)
        part += __shfl_xor(part, off);
    if (l == 0) partial[wid] = part;
    __syncthreads();
    if (tid < 4)
        pooled[b * 256 + c0 + tid] = partial[tid] + partial[tid + 4];
}

// ---------------------------------------------------------------------------
// K2: MLP tail. 16 blocks x 512 thr (R9 verbatim).
// ---------------------------------------------------------------------------
__device__ __forceinline__ void dense512(
    const float* __restrict__ W, const float* __restrict__ Bv,
    const float* in_lds, float* out_lds, int tid, bool do_relu)
{
    int o = tid >> 1, p = tid & 1;
    const float* wr = W + o * 256 + p * 128;
    const float* ir = in_lds + p * 128;
    float acc = 0.f;
    #pragma unroll
    for (int k = 0; k < 128; k += 4) {
        float4 wv = *(const float4*)(wr + k);
        float4 iv = *(const float4*)(ir + k);
        acc = fmaf(wv.x, iv.x, acc); acc = fmaf(wv.y, iv.y, acc);
        acc = fmaf(wv.z, iv.z, acc); acc = fmaf(wv.w, iv.w, acc);
    }
    acc += __shfl_xor(acc, 1);
    if (p == 0) {
        acc += Bv[o];
        out_lds[o] = do_relu ? fmaxf(acc, 0.f) : acc;
    }
}

__global__ __launch_bounds__(512) void tail_kernel(
    const float* __restrict__ pooled,
    const float* __restrict__ L1w, const float* __restrict__ L1b,
    const float* __restrict__ L2w, const float* __restrict__ L2b,
    const float* __restrict__ C1w, const float* __restrict__ C1b,
    const float* __restrict__ C2w, const float* __restrict__ C2b,
    float* __restrict__ out)
{
    __shared__ float za[256], zb[256];
    int bt = blockIdx.x, tid = threadIdx.x;
    if (tid < 256) za[tid] = pooled[bt * 256 + tid];
    __syncthreads();
    dense512(L1w, L1b, za, zb, tid, true);
    __syncthreads();
    dense512(L2w, L2b, zb, za, tid, false);
    __syncthreads();
    dense512(C1w, C1b, za, zb, tid, true);
    __syncthreads();
    if (tid < 320) {   // cls2: 10 outputs x 32 lanes, 8 k each
        int o = tid >> 5, kb = tid & 31;
        const float* wr = C2w + o * 256 + kb * 8;
        const float* ir = zb + kb * 8;
        float4 w0 = *(const float4*)(wr);
        float4 w1v = *(const float4*)(wr + 4);
        float4 i0 = *(const float4*)(ir);
        float4 i1 = *(const float4*)(ir + 4);
        float p = fmaf(w0.x,i0.x, fmaf(w0.y,i0.y, fmaf(w0.z,i0.z,
                  fmaf(w0.w,i0.w, fmaf(w1v.x,i1.x, fmaf(w1v.y,i1.y,
                  fmaf(w1v.z,i1.z, w1v.w*i1.w)))))));
        #pragma unroll
        for (int off = 16; off > 0; off >>= 1)
            p += __shfl_xor(p, off, 32);
        if (kb == 0) out[bt * 10 + o] = p + C2b[o];
    }
}

// ---------------------------------------------------------------------------
extern "C" void kernel_launch(void* const* d_in, const int* in_sizes, int n_in,
                              void* d_out, int out_size, void* d_ws, size_t ws_size,
                              hipStream_t stream)
{
    (void)in_sizes; (void)n_in; (void)out_size; (void)ws_size;
    const float* x       = (const float*)d_in[0];
    const float* conv1_w = (const float*)d_in[1];
    const float* conv1_b = (const float*)d_in[2];
    const float* conv2_w = (const float*)d_in[3];
    const float* conv2_b = (const float*)d_in[4];
    const float* pool_w  = (const float*)d_in[5];
    const float* lin1_w  = (const float*)d_in[6];
    const float* lin1_b  = (const float*)d_in[7];
    const float* lin2_w  = (const float*)d_in[8];
    const float* lin2_b  = (const float*)d_in[9];
    const float* cls1_w  = (const float*)d_in[10];
    const float* cls1_b  = (const float*)d_in[11];
    const float* cls2_w  = (const float*)d_in[12];
    const float* cls2_b  = (const float*)d_in[13];
    float* out = (float*)d_out;

    float* pooled = (float*)d_ws;        // 4096 floats

    conv_pool_kernel<<<1024, 512, 0, stream>>>(
        x, conv1_w, conv1_b, conv2_w, conv2_b, pool_w, pooled);
    tail_kernel<<<16, 512, 0, stream>>>(pooled,
        lin1_w, lin1_b, lin2_w, lin2_b, cls1_w, cls1_b, cls2_w, cls2_b, out);
}